// Round 10
// baseline (2387.179 us; speedup 1.0000x reference)
//
#include <hip/hip_runtime.h>
#include <cstdint>
#include <cstddef>

#define M_DIM 4096
#define K_DIM 4096
#define N_DIM 11008
#define BM 256
#define BN 256
#define BKB 64                        /* K bytes per step (2 k-slices of K=32) */
#define NT (K_DIM / BKB)              /* 64 steps */
#define NTM (M_DIM / BM)              /* 16 */
#define NTN (N_DIM / BN)              /* 43 */
#define SLOT 32768                    /* A 16KB + B 16KB */
#define B_OFF 16384

typedef int   int4v   __attribute__((ext_vector_type(4)));
typedef int   int16v  __attribute__((ext_vector_type(16)));
typedef float float4v __attribute__((ext_vector_type(4)));

__device__ __forceinline__ void gload_lds16(const void* g, void* l) {
  __builtin_amdgcn_global_load_lds(
      (const __attribute__((address_space(1))) unsigned int*)g,
      (__attribute__((address_space(3))) unsigned int*)l, 16, 0, 0);
}

// ---------------- x quantization: fp32 -> int8 ----------------
__global__ void quant_x_kernel(const float* __restrict__ x,
                               const float* __restrict__ scale_p,
                               const int* __restrict__ off_p,
                               signed char* __restrict__ xq, int total16) {
  const float inv = 1.0f / scale_p[0];
  const float off = (float)off_p[0];
  int tid = blockIdx.x * blockDim.x + threadIdx.x;
  int stride = gridDim.x * blockDim.x;
  const float4v* x4 = (const float4v*)x;
  int4v* out4 = (int4v*)xq;
  for (int i = tid; i < total16; i += stride) {
    int4v o;
#pragma unroll
    for (int j = 0; j < 4; ++j) {
      float4v v = x4[(size_t)i * 4 + j];
      int r = 0;
#pragma unroll
      for (int e = 0; e < 4; ++e) {
        float q = rintf(v[e] * inv) + off;     // round-half-even, matches jnp.round
        q = fminf(fmaxf(q, -128.0f), 127.0f);
        int qi = (int)q;
        r |= (qi & 0xff) << (8 * e);
      }
      o[j] = r;
    }
    out4[i] = o;
  }
}

// ---------------- weight pack: int32 carrier -> int8 ----------------
__global__ void pack_w_kernel(const int* __restrict__ w,
                              signed char* __restrict__ wq, int total16) {
  int tid = blockIdx.x * blockDim.x + threadIdx.x;
  int stride = gridDim.x * blockDim.x;
  const int4v* w4 = (const int4v*)w;
  int4v* out4 = (int4v*)wq;
  for (int i = tid; i < total16; i += stride) {
    int4v o;
#pragma unroll
    for (int j = 0; j < 4; ++j) {
      int4v v = w4[(size_t)i * 4 + j];
      o[j] = (v[0] & 0xff) | ((v[1] & 0xff) << 8) |
             ((v[2] & 0xff) << 16) | ((v[3] & 0xff) << 24);
    }
    out4[i] = o;
  }
}

// ---- int8 GEMM: 256x256, 4 waves x 128x128, mfma_i32_32x32x32_i8, ----
// ---- BKB=64, 64KB LDS double-buffer -> 2 blocks/CU, 1 barrier/step. ----
// A: xq [M][K] int8, B: wq [N][K] int8 (B^T), out fp32 [M][N]
// LDS: 64-B rows; LDS[R*64 + c] = tile[R][c ^ ((R&3)<<4)] (16B-chunk XOR
// swizzle, involution).  DMA dest linear (wave base + lane*16), global
// source pre-swizzled (m173).  ds_read: lane l, 32-row block m, k-slice ks:
// addr = R*64 + ((ckb ^ (ks<<5)), ckb = ((l>>5)^(l&3))<<4 -> <=2-way conflict.
__global__ __launch_bounds__(256, 2) void gemm_i8_kernel(
    const signed char* __restrict__ A,
    const signed char* __restrict__ B,
    const int* __restrict__ qbias,
    const float* __restrict__ dscale,
    float* __restrict__ out) {
  __shared__ __attribute__((aligned(16))) signed char lds[2 * SLOT];  // 64 KB

  const int tid  = threadIdx.x;
  const int lane = tid & 63;
  const int wv   = tid >> 6;   // 0..3
  const int wr   = wv >> 1;    // 0..1  (M half: 128 rows)
  const int wc   = wv & 1;     // 0..1  (N half: 128 cols)

  // XCD swizzle (R6-style): xcd owns tm pair {2x,2x+1}; tn slow.
  int bid = blockIdx.x;
  int s   = bid >> 3;                 // 0..85
  int tm  = 2 * (bid & 7) + (s & 1);  // 0..15
  int tn  = s >> 1;                   // 0..42

  // ---- staging: thread t, load j (j=0..3): dest chunk j*256 + t ----
  // dest row = j*64 + (t>>2), chunk q = t&3; source col = (q ^ (row&3))*16.
  const int swz = (((tid & 3) ^ ((tid >> 2) & 3)) << 4);
  const signed char* sA = A + (size_t)(tm * BM + (tid >> 2)) * K_DIM + swz;
  const signed char* sB = B + (size_t)(tn * BN + (tid >> 2)) * K_DIM + swz;
  const int dst0 = tid << 4;

#define STG(KW, SO) do {                                                      \
    _Pragma("unroll") for (int j = 0; j < 4; ++j) {                           \
      gload_lds16(sA + (size_t)j * 64 * K_DIM + (size_t)(KW) * BKB,           \
                  lds + (SO) + j * 4096 + dst0);                              \
      gload_lds16(sB + (size_t)j * 64 * K_DIM + (size_t)(KW) * BKB,           \
                  lds + (SO) + B_OFF + j * 4096 + dst0);                      \
    } } while (0)

  // ---- ds_read constants ----
  const int ckb = ((((lane >> 5) ^ lane) & 3) << 4);        // ks=0 chunk; ks=1: ^0x20
  const int rdA = (wr * 128 + (lane & 31)) * 64;            // + m*2048
  const int rdB = B_OFF + (wc * 128 + (lane & 31)) * 64;    // + n*2048

#define WAITK(n) do {                                                         \
    asm volatile("s_waitcnt lgkmcnt(" #n ")" ::: "memory");                   \
    __builtin_amdgcn_sched_barrier(0); } while (0)
#define MMG(m) do {                                                           \
    __builtin_amdgcn_s_setprio(1);                                            \
    _Pragma("unroll") for (int ks = 0; ks < 2; ++ks)                          \
      _Pragma("unroll") for (int n = 0; n < 4; ++n)                           \
        acc[m][n] = __builtin_amdgcn_mfma_i32_32x32x32_i8(                    \
            afr[m][ks], bfr[n][ks], acc[m][n], 0, 0, 0);                      \
    __builtin_amdgcn_s_setprio(0); } while (0)

  // Issue order: B (8 reads), A m=0..3 (8 reads) -> lgkm(6/4/2/0) drains
  // {B+A0}, A1, A2, A3 group-by-group under the preceding MFMA cluster.
#define STEP(KT, SB, NB) do {                                                 \
    _Pragma("unroll") for (int n = 0; n < 4; ++n)                             \
      _Pragma("unroll") for (int ks = 0; ks < 2; ++ks)                        \
        bfr[n][ks] = *(const int4v*)(lds + (SB) + rdB + n * 2048 +            \
                                     (ckb ^ (ks << 5)));                      \
    _Pragma("unroll") for (int m = 0; m < 4; ++m)                             \
      _Pragma("unroll") for (int ks = 0; ks < 2; ++ks)                        \
        afr[m][ks] = *(const int4v*)(lds + (SB) + rdA + m * 2048 +            \
                                     (ckb ^ (ks << 5)));                      \
    STG(((KT) + 1) & (NT - 1), NB);                                           \
    WAITK(6); MMG(0);                                                         \
    WAITK(4); MMG(1);                                                         \
    WAITK(2); MMG(2);                                                         \
    WAITK(0); MMG(3);                                                         \
    asm volatile("s_waitcnt vmcnt(0)" ::: "memory");                          \
    __builtin_amdgcn_s_barrier();                                             \
  } while (0)

  int16v acc[4][4];
#pragma unroll
  for (int i = 0; i < 4; ++i)
#pragma unroll
    for (int j = 0; j < 4; ++j)
#pragma unroll
      for (int e = 0; e < 16; ++e) acc[i][j][e] = 0;

  int4v afr[4][2], bfr[4][2];

  // ---- prologue: stage step 0 ----
  STG(0, 0);
  asm volatile("s_waitcnt vmcnt(0)" ::: "memory");
  __builtin_amdgcn_s_barrier();

  for (int t = 0; t < NT; t += 2) {
    STEP(t,     0,    SLOT);
    STEP(t + 1, SLOT, 0);
  }
#undef STEP
#undef MMG
#undef WAITK
#undef STG

  // ---- epilogue: out[m][n] = (acc + qbias[n]) * dscale[n] ----
  // 32x32 C/D: col = lane&31, row = (r&3) + 8*(r>>2) + 4*(lane>>5)
  const int col = lane & 31;
  const int rhi = (lane >> 5) * 4;
  const int gm0 = tm * BM + wr * 128;
  const int gn0 = tn * BN + wc * 128;
#pragma unroll
  for (int n = 0; n < 4; ++n) {
    int gn = gn0 + n * 32 + col;
    float ds = dscale[gn];
    int qb = qbias[gn];
#pragma unroll
    for (int m = 0; m < 4; ++m) {
      int base = gm0 + m * 32 + rhi;
#pragma unroll
      for (int r = 0; r < 16; ++r) {
        int row = base + (r & 3) + 8 * (r >> 2);
        out[(size_t)row * N_DIM + gn] = (float)(acc[m][n][r] + qb) * ds;
      }
    }
  }
}

extern "C" void kernel_launch(void* const* d_in, const int* in_sizes, int n_in,
                              void* d_out, int out_size, void* d_ws, size_t ws_size,
                              hipStream_t stream) {
  const float* x      = (const float*)d_in[0];
  const int*   w      = (const int*)d_in[1];
  const float* dscale = (const float*)d_in[2];
  const float* iscale = (const float*)d_in[3];
  const int*   ioff   = (const int*)d_in[4];
  const int*   qbias  = (const int*)d_in[5];
  float* out = (float*)d_out;

  const size_t xq_bytes = (size_t)M_DIM * K_DIM;        // 16 MB
  const size_t wq_bytes = (size_t)N_DIM * K_DIM;        // 45 MB
  if (ws_size < xq_bytes + wq_bytes) return;

  signed char* xq = (signed char*)d_ws;
  signed char* wq = (signed char*)d_ws + xq_bytes;

  quant_x_kernel<<<2048, 256, 0, stream>>>(x, iscale, ioff, xq, M_DIM * K_DIM / 16);
  pack_w_kernel<<<2048, 256, 0, stream>>>(w, wq, N_DIM * K_DIM / 16);
  gemm_i8_kernel<<<NTM * NTN, 256, 0, stream>>>(xq, wq, qbias, dscale, out);
}

// Round 11
// 258.229 us; speedup vs baseline: 9.2444x; 9.2444x over previous
//
#include <hip/hip_runtime.h>
#include <cstdint>
#include <cstddef>

#define M_DIM 4096
#define K_DIM 4096
#define N_DIM 11008
#define BM 128
#define BN 256
#define BKB 64                        /* K bytes per step (one K=64 slice) */
#define NT (K_DIM / BKB)              /* 64 steps */
#define NTM (M_DIM / BM)              /* 32 */
#define NTN (N_DIM / BN)              /* 43 */
#define SLOT 24576                    /* A 8KB + B 16KB */
#define B_OFF 8192

typedef int   int4v   __attribute__((ext_vector_type(4)));
typedef float float4v __attribute__((ext_vector_type(4)));

__device__ __forceinline__ void gload_lds16(const void* g, void* l) {
  __builtin_amdgcn_global_load_lds(
      (const __attribute__((address_space(1))) unsigned int*)g,
      (__attribute__((address_space(3))) unsigned int*)l, 16, 0, 0);
}

// ---------------- x quantization: fp32 -> int8 ----------------
__global__ void quant_x_kernel(const float* __restrict__ x,
                               const float* __restrict__ scale_p,
                               const int* __restrict__ off_p,
                               signed char* __restrict__ xq, int total16) {
  const float inv = 1.0f / scale_p[0];
  const float off = (float)off_p[0];
  int tid = blockIdx.x * blockDim.x + threadIdx.x;
  int stride = gridDim.x * blockDim.x;
  const float4v* x4 = (const float4v*)x;
  int4v* out4 = (int4v*)xq;
  for (int i = tid; i < total16; i += stride) {
    int4v o;
#pragma unroll
    for (int j = 0; j < 4; ++j) {
      float4v v = x4[(size_t)i * 4 + j];
      int r = 0;
#pragma unroll
      for (int e = 0; e < 4; ++e) {
        float q = rintf(v[e] * inv) + off;     // round-half-even, matches jnp.round
        q = fminf(fmaxf(q, -128.0f), 127.0f);
        int qi = (int)q;
        r |= (qi & 0xff) << (8 * e);
      }
      o[j] = r;
    }
    out4[i] = o;
  }
}

// ---------------- weight pack: int32 carrier -> int8 ----------------
__global__ void pack_w_kernel(const int* __restrict__ w,
                              signed char* __restrict__ wq, int total16) {
  int tid = blockIdx.x * blockDim.x + threadIdx.x;
  int stride = gridDim.x * blockDim.x;
  const int4v* w4 = (const int4v*)w;
  int4v* out4 = (int4v*)wq;
  for (int i = tid; i < total16; i += stride) {
    int4v o;
#pragma unroll
    for (int j = 0; j < 4; ++j) {
      int4v v = w4[(size_t)i * 4 + j];
      o[j] = (v[0] & 0xff) | ((v[1] & 0xff) << 8) |
             ((v[2] & 0xff) << 16) | ((v[3] & 0xff) << 24);
    }
    out4[i] = o;
  }
}

// ---- int8 GEMM: 128x256 block, 4 waves x (64x128), ring-3, 2 blocks/CU ----
// A: xq [M][K] int8, B: wq [N][K] int8 (B^T), out fp32 [M][N]
// LDS: 64-B rows, 16-row frags (1 KB).  LDS[frag*1024 + r*64 + p*16] holds
// tile[frag*16+r][ (p ^ (r&3))*16 .. +16 ] -- XOR involution on the 16B chunk.
// DMA dest linear (frag base + lane*16); global SOURCE pre-swizzled (m173).
// ds_read: lane l, frag f: addr f*1024 + (l&15)*64 + (((l>>4)^l)&3)*16
//   -> 2 lanes/bank (free, m136).  A frags 0-7 at 0, B frags 0-15 at +8KB.
// Per step: one barrier; 12 ds_reads up front; stage t+2 (ring-3, all waits
// >= 1 full step aged); lgkm(4)/lgkm(0) split MFMA into 2x16; vmcnt(6).
__global__ __launch_bounds__(256, 2) void gemm_i8_kernel(
    const signed char* __restrict__ A,
    const signed char* __restrict__ B,
    const int* __restrict__ qbias,
    const float* __restrict__ dscale,
    float* __restrict__ out) {
  __shared__ __attribute__((aligned(16))) signed char lds[3 * SLOT];  // 72 KB

  const int tid  = threadIdx.x;
  const int lane = tid & 63;
  const int wv   = tid >> 6;   // 0..3
  const int wr   = wv >> 1;    // 0..1  (M half: 64 rows)
  const int wc   = wv & 1;     // 0..1  (N half: 128 cols)

  // XCD swizzle: 1376 blocks, 172/XCD; xcd owns tm {4x..4x+3} (A stripe 2MB
  // L2-resident); 4 dispatch-adjacent blocks share one 1MB B panel.
  int bid = blockIdx.x;
  int s   = bid >> 3;                  // 0..171
  int tm  = 4 * (bid & 7) + (s & 3);   // 0..31
  int tn  = s >> 2;                    // 0..42

  // ---- staging (pre-swizzled source, linear dest) ----
  const int csw = (((lane & 3) ^ ((lane >> 2) & 3)) << 4);
  const signed char* sA0 = A + (size_t)(tm * BM + wv * 16 + (lane >> 2)) * K_DIM + csw;
  const signed char* sB0 = B + (size_t)(tn * BN + wv * 64 + (lane >> 2)) * K_DIM + csw;
  const int dA0 = wv * 1024 + lane * 16;                 // frag wv   (+4096: frag wv+4)
  const int dB0 = B_OFF + wv * 4096 + lane * 16;         // frags wv*4 + j

#define STG(KT, SO) do {                                                      \
    gload_lds16(sA0 + (size_t)(KT) * BKB,                    lds + (SO) + dA0);        \
    gload_lds16(sA0 + (size_t)64 * K_DIM + (size_t)(KT) * BKB, lds + (SO) + dA0 + 4096); \
    _Pragma("unroll") for (int j = 0; j < 4; ++j)                             \
      gload_lds16(sB0 + (size_t)j * 16 * K_DIM + (size_t)(KT) * BKB,          \
                  lds + (SO) + dB0 + j * 1024);                               \
  } while (0)

  // ---- ds_read constants ----
  const int rp  = ((((lane >> 4) ^ lane) & 3) << 4);
  const int rdA = (wr * 4) * 1024 + (lane & 15) * 64 + rp;          // + m*1024
  const int rdB = B_OFF + (wc * 8) * 1024 + (lane & 15) * 64 + rp;  // + n*1024

#define LG(n) do {                                                            \
    asm volatile("s_waitcnt lgkmcnt(" #n ")" ::: "memory");                   \
    __builtin_amdgcn_sched_barrier(0); } while (0)
#define MMH(N0) do {                                                          \
    __builtin_amdgcn_s_setprio(1);                                            \
    _Pragma("unroll") for (int m = 0; m < 4; ++m)                             \
      _Pragma("unroll") for (int n = 0; n < 4; ++n)                           \
        acc[m][(N0) + n] = __builtin_amdgcn_mfma_i32_16x16x64_i8(             \
            afr[m], bfr[(N0) + n], acc[m][(N0) + n], 0, 0, 0);                \
    __builtin_amdgcn_s_setprio(0); } while (0)

  // STEP: read slot SB (12 ds), optionally stage KT2 into S2 (6 vmem),
  // MFMA 2x16 with counted lgkm, then VM wait + barrier per mode.
#define STEP(SB, DO_STG, KT2, S2, VMODE) do {                                 \
    _Pragma("unroll") for (int m = 0; m < 4; ++m)                             \
      afr[m] = *(const int4v*)(lds + (SB) + rdA + m * 1024);                  \
    _Pragma("unroll") for (int n = 0; n < 8; ++n)                             \
      bfr[n] = *(const int4v*)(lds + (SB) + rdB + n * 1024);                  \
    if (DO_STG) STG((KT2), (S2));                                             \
    LG(4);                                                                    \
    MMH(0);                                                                   \
    LG(0);                                                                    \
    MMH(4);                                                                   \
    if ((VMODE) == 0) { asm volatile("s_waitcnt vmcnt(6)" ::: "memory"); }    \
    else if ((VMODE) == 1) { asm volatile("s_waitcnt vmcnt(0)" ::: "memory"); } \
    if ((VMODE) != 2) __builtin_amdgcn_s_barrier();                           \
  } while (0)

  int4v acc[4][8];
#pragma unroll
  for (int i = 0; i < 4; ++i)
#pragma unroll
    for (int j = 0; j < 8; ++j) acc[i][j] = (int4v){0, 0, 0, 0};

  int4v afr[4], bfr[8];

  // ---- prologue: stage steps 0,1; slot0 landed, slot1 in flight ----
  STG(0, 0);
  STG(1, SLOT);
  asm volatile("s_waitcnt vmcnt(6)" ::: "memory");
  __builtin_amdgcn_s_barrier();

  int c0 = 0, c1 = SLOT, c2 = 2 * SLOT;   // slots of t, t+1, t+2
  for (int t = 0; t < NT - 2; ++t) {
    STEP(c0, 1, t + 2, c2, 0);
    int tmp = c0; c0 = c1; c1 = c2; c2 = tmp;
  }
  STEP(c0, 0, 0, 0, 1);                   // t = NT-2: no stage, vmcnt(0)
  { int tmp = c0; c0 = c1; c1 = c2; c2 = tmp; }
  STEP(c0, 0, 0, 0, 2);                   // t = NT-1: no stage, no wait
#undef STEP
#undef MMH
#undef LG
#undef STG

  // ---- epilogue: out[m][n] = (acc + qbias[n]) * dscale[n] ----
  const int col = lane & 15;
  const int rb  = (lane >> 4) * 4;
  const int gm0 = tm * BM + wr * 64;
  const int gn0 = tn * BN + wc * 128;
#pragma unroll
  for (int n = 0; n < 8; ++n) {
    int gn = gn0 + n * 16 + col;
    float ds = dscale[gn];
    int qb = qbias[gn];
#pragma unroll
    for (int m = 0; m < 4; ++m) {
      int gm = gm0 + m * 16 + rb;
#pragma unroll
      for (int j = 0; j < 4; ++j)
        out[(size_t)(gm + j) * N_DIM + gn] = (float)(acc[m][n][j] + qb) * ds;
    }
  }
}

extern "C" void kernel_launch(void* const* d_in, const int* in_sizes, int n_in,
                              void* d_out, int out_size, void* d_ws, size_t ws_size,
                              hipStream_t stream) {
  const float* x      = (const float*)d_in[0];
  const int*   w      = (const int*)d_in[1];
  const float* dscale = (const float*)d_in[2];
  const float* iscale = (const float*)d_in[3];
  const int*   ioff   = (const int*)d_in[4];
  const int*   qbias  = (const int*)d_in[5];
  float* out = (float*)d_out;

  const size_t xq_bytes = (size_t)M_DIM * K_DIM;        // 16 MB
  const size_t wq_bytes = (size_t)N_DIM * K_DIM;        // 45 MB
  if (ws_size < xq_bytes + wq_bytes) return;

  signed char* xq = (signed char*)d_ws;
  signed char* wq = (signed char*)d_ws + xq_bytes;

  quant_x_kernel<<<2048, 256, 0, stream>>>(x, iscale, ioff, xq, M_DIM * K_DIM / 16);
  pack_w_kernel<<<2048, 256, 0, stream>>>(w, wq, N_DIM * K_DIM / 16);
  gemm_i8_kernel<<<NTM * NTN, 256, 0, stream>>>(xq, wq, qbias, dscale, out);
}

// Round 12
// 258.127 us; speedup vs baseline: 9.2481x; 1.0004x over previous
//
#include <hip/hip_runtime.h>
#include <cstdint>
#include <cstddef>

#define M_DIM 4096
#define K_DIM 4096
#define N_DIM 11008
#define BM 128
#define BN 256
#define BKB 64                        /* K bytes per step (one K=64 slice) */
#define NT (K_DIM / BKB)              /* 64 steps */
#define NTM (M_DIM / BM)              /* 32 */
#define NTN (N_DIM / BN)              /* 43 */
#define SLOT 24576                    /* A 8KB + B 16KB */
#define B_OFF 8192

typedef int   int4v   __attribute__((ext_vector_type(4)));
typedef float float4v __attribute__((ext_vector_type(4)));

__device__ __forceinline__ void gload_lds16(const void* g, void* l) {
  __builtin_amdgcn_global_load_lds(
      (const __attribute__((address_space(1))) unsigned int*)g,
      (__attribute__((address_space(3))) unsigned int*)l, 16, 0, 0);
}

// ---------------- x quantization: fp32 -> int8 ----------------
__global__ void quant_x_kernel(const float* __restrict__ x,
                               const float* __restrict__ scale_p,
                               const int* __restrict__ off_p,
                               signed char* __restrict__ xq, int total16) {
  const float inv = 1.0f / scale_p[0];
  const float off = (float)off_p[0];
  int tid = blockIdx.x * blockDim.x + threadIdx.x;
  int stride = gridDim.x * blockDim.x;
  const float4v* x4 = (const float4v*)x;
  int4v* out4 = (int4v*)xq;
  for (int i = tid; i < total16; i += stride) {
    int4v o;
#pragma unroll
    for (int j = 0; j < 4; ++j) {
      float4v v = x4[(size_t)i * 4 + j];
      int r = 0;
#pragma unroll
      for (int e = 0; e < 4; ++e) {
        float q = rintf(v[e] * inv) + off;     // round-half-even, matches jnp.round
        q = fminf(fmaxf(q, -128.0f), 127.0f);
        int qi = (int)q;
        r |= (qi & 0xff) << (8 * e);
      }
      o[j] = r;
    }
    out4[i] = o;
  }
}

// ---------------- weight pack: int32 carrier -> int8 ----------------
__global__ void pack_w_kernel(const int* __restrict__ w,
                              signed char* __restrict__ wq, int total16) {
  int tid = blockIdx.x * blockDim.x + threadIdx.x;
  int stride = gridDim.x * blockDim.x;
  const int4v* w4 = (const int4v*)w;
  int4v* out4 = (int4v*)wq;
  for (int i = tid; i < total16; i += stride) {
    int4v o;
#pragma unroll
    for (int j = 0; j < 4; ++j) {
      int4v v = w4[(size_t)i * 4 + j];
      o[j] = (v[0] & 0xff) | ((v[1] & 0xff) << 8) |
             ((v[2] & 0xff) << 16) | ((v[3] & 0xff) << 24);
    }
    out4[i] = o;
  }
}

// ---- int8 GEMM: 128x256 block, 4 waves x (64x128), ring-3, 2 blocks/CU ----
// A: xq [M][K] int8, B: wq [N][K] int8 (B^T), out fp32 [M][N]
// LDS: 64-B rows, 16-row frags (1 KB).  Physical chunk p of row r holds
// logical k-chunk p ^ f(r), f(r) = (r>>1)&3  (XOR involution).
// Conflict math: row base bank = (r*16)%32 (parity classes); within the 8
// rows of a parity class f(r) covers each chunk exactly twice -> every bank
// 2x per 16-lane group = conflict-free (m136).  [R11 used f=r&3: rows
// {0,4,8,12} collided 4-way -> 1.69e7 conflicts; this is the fix.]
// DMA dest linear; global SOURCE pre-swizzled (m173).
// Per step: one barrier; 12 ds_reads up front; stage t+2 (ring-3, all waits
// >= 1 full step aged); lgkm(4)/lgkm(0) split MFMA into 2x16; vmcnt(6).
__global__ __launch_bounds__(256, 2) void gemm_i8_kernel(
    const signed char* __restrict__ A,
    const signed char* __restrict__ B,
    const int* __restrict__ qbias,
    const float* __restrict__ dscale,
    float* __restrict__ out) {
  __shared__ __attribute__((aligned(16))) signed char lds[3 * SLOT];  // 72 KB

  const int tid  = threadIdx.x;
  const int lane = tid & 63;
  const int wv   = tid >> 6;   // 0..3
  const int wr   = wv >> 1;    // 0..1  (M half: 64 rows)
  const int wc   = wv & 1;     // 0..1  (N half: 128 cols)

  // XCD swizzle: 1376 blocks, 172/XCD; xcd owns tm {4x..4x+3} (A stripe 2MB
  // L2-resident); 4 dispatch-adjacent blocks share one 1MB B panel.
  int bid = blockIdx.x;
  int s   = bid >> 3;                  // 0..171
  int tm  = 4 * (bid & 7) + (s & 3);   // 0..31
  int tn  = s >> 2;                    // 0..42

  // ---- staging (pre-swizzled source, linear dest) ----
  // dest row r_d = lane>>2, physical chunk p_d = lane&3;
  // source logical chunk = p_d ^ f(r_d) = (lane&3) ^ ((lane>>3)&3).
  const int csw = (((lane & 3) ^ ((lane >> 3) & 3)) << 4);
  const signed char* sA0 = A + (size_t)(tm * BM + wv * 16 + (lane >> 2)) * K_DIM + csw;
  const signed char* sB0 = B + (size_t)(tn * BN + wv * 64 + (lane >> 2)) * K_DIM + csw;
  const int dA0 = wv * 1024 + lane * 16;                 // frag wv   (+4096: frag wv+4)
  const int dB0 = B_OFF + wv * 4096 + lane * 16;         // frags wv*4 + j

#define STG(KT, SO) do {                                                      \
    gload_lds16(sA0 + (size_t)(KT) * BKB,                    lds + (SO) + dA0);        \
    gload_lds16(sA0 + (size_t)64 * K_DIM + (size_t)(KT) * BKB, lds + (SO) + dA0 + 4096); \
    _Pragma("unroll") for (int j = 0; j < 4; ++j)                             \
      gload_lds16(sB0 + (size_t)j * 16 * K_DIM + (size_t)(KT) * BKB,          \
                  lds + (SO) + dB0 + j * 1024);                               \
  } while (0)

  // ---- ds_read constants ----
  // lane l: row r = l&15, logical chunk q = l>>4; physical chunk = q ^ f(r)
  // = ((l>>4) ^ (l>>1)) & 3.
  const int rp  = ((((lane >> 4) ^ (lane >> 1)) & 3) << 4);
  const int rdA = (wr * 4) * 1024 + (lane & 15) * 64 + rp;          // + m*1024
  const int rdB = B_OFF + (wc * 8) * 1024 + (lane & 15) * 64 + rp;  // + n*1024

#define LG(n) do {                                                            \
    asm volatile("s_waitcnt lgkmcnt(" #n ")" ::: "memory");                   \
    __builtin_amdgcn_sched_barrier(0); } while (0)
#define MMH(N0) do {                                                          \
    __builtin_amdgcn_s_setprio(1);                                            \
    _Pragma("unroll") for (int m = 0; m < 4; ++m)                             \
      _Pragma("unroll") for (int n = 0; n < 4; ++n)                           \
        acc[m][(N0) + n] = __builtin_amdgcn_mfma_i32_16x16x64_i8(             \
            afr[m], bfr[(N0) + n], acc[m][(N0) + n], 0, 0, 0);                \
    __builtin_amdgcn_s_setprio(0); } while (0)

  // STEP: read slot SB (12 ds), optionally stage KT2 into S2 (6 vmem),
  // MFMA 2x16 with counted lgkm, then VM wait + barrier per mode.
#define STEP(SB, DO_STG, KT2, S2, VMODE) do {                                 \
    _Pragma("unroll") for (int m = 0; m < 4; ++m)                             \
      afr[m] = *(const int4v*)(lds + (SB) + rdA + m * 1024);                  \
    _Pragma("unroll") for (int n = 0; n < 8; ++n)                             \
      bfr[n] = *(const int4v*)(lds + (SB) + rdB + n * 1024);                  \
    if (DO_STG) STG((KT2), (S2));                                             \
    LG(4);                                                                    \
    MMH(0);                                                                   \
    LG(0);                                                                    \
    MMH(4);                                                                   \
    if ((VMODE) == 0) { asm volatile("s_waitcnt vmcnt(6)" ::: "memory"); }    \
    else if ((VMODE) == 1) { asm volatile("s_waitcnt vmcnt(0)" ::: "memory"); } \
    if ((VMODE) != 2) __builtin_amdgcn_s_barrier();                           \
  } while (0)

  int4v acc[4][8];
#pragma unroll
  for (int i = 0; i < 4; ++i)
#pragma unroll
    for (int j = 0; j < 8; ++j) acc[i][j] = (int4v){0, 0, 0, 0};

  int4v afr[4], bfr[8];

  // ---- prologue: stage steps 0,1; slot0 landed, slot1 in flight ----
  STG(0, 0);
  STG(1, SLOT);
  asm volatile("s_waitcnt vmcnt(6)" ::: "memory");
  __builtin_amdgcn_s_barrier();

  int c0 = 0, c1 = SLOT, c2 = 2 * SLOT;   // slots of t, t+1, t+2
  for (int t = 0; t < NT - 2; ++t) {
    STEP(c0, 1, t + 2, c2, 0);
    int tmp = c0; c0 = c1; c1 = c2; c2 = tmp;
  }
  STEP(c0, 0, 0, 0, 1);                   // t = NT-2: no stage, vmcnt(0)
  { int tmp = c0; c0 = c1; c1 = c2; c2 = tmp; }
  STEP(c0, 0, 0, 0, 2);                   // t = NT-1: no stage, no wait
#undef STEP
#undef MMH
#undef LG
#undef STG

  // ---- epilogue: out[m][n] = (acc + qbias[n]) * dscale[n] ----
  const int col = lane & 15;
  const int rb  = (lane >> 4) * 4;
  const int gm0 = tm * BM + wr * 64;
  const int gn0 = tn * BN + wc * 128;
#pragma unroll
  for (int n = 0; n < 8; ++n) {
    int gn = gn0 + n * 16 + col;
    float ds = dscale[gn];
    int qb = qbias[gn];
#pragma unroll
    for (int m = 0; m < 4; ++m) {
      int gm = gm0 + m * 16 + rb;
#pragma unroll
      for (int j = 0; j < 4; ++j)
        out[(size_t)(gm + j) * N_DIM + gn] = (float)(acc[m][n][j] + qb) * ds;
    }
  }
}

extern "C" void kernel_launch(void* const* d_in, const int* in_sizes, int n_in,
                              void* d_out, int out_size, void* d_ws, size_t ws_size,
                              hipStream_t stream) {
  const float* x      = (const float*)d_in[0];
  const int*   w      = (const int*)d_in[1];
  const float* dscale = (const float*)d_in[2];
  const float* iscale = (const float*)d_in[3];
  const int*   ioff   = (const int*)d_in[4];
  const int*   qbias  = (const int*)d_in[5];
  float* out = (float*)d_out;

  const size_t xq_bytes = (size_t)M_DIM * K_DIM;        // 16 MB
  const size_t wq_bytes = (size_t)N_DIM * K_DIM;        // 45 MB
  if (ws_size < xq_bytes + wq_bytes) return;

  signed char* xq = (signed char*)d_ws;
  signed char* wq = (signed char*)d_ws + xq_bytes;

  quant_x_kernel<<<2048, 256, 0, stream>>>(x, iscale, ioff, xq, M_DIM * K_DIM / 16);
  pack_w_kernel<<<2048, 256, 0, stream>>>(w, wq, M_DIM ? N_DIM * K_DIM / 16 : 0);
  gemm_i8_kernel<<<NTM * NTN, 256, 0, stream>>>(xq, wq, qbias, dscale, out);
}